// Round 13
// baseline (1108.923 us; speedup 1.0000x reference)
//
#include <hip/hip_runtime.h>

#define DIM 512
#define NROWS 131072

typedef __attribute__((ext_vector_type(8))) __bf16 bf16x8;
typedef __attribute__((ext_vector_type(4))) float f32x4;

__device__ __forceinline__ unsigned short f2bf(float f) {
  unsigned u = __builtin_bit_cast(unsigned, f);
  return (unsigned short)((u + 0x7FFFu + ((u >> 16) & 1u)) >> 16);
}
__device__ __forceinline__ float bf2f(unsigned short u) {
  return __builtin_bit_cast(float, (unsigned)u << 16);
}
__device__ __forceinline__ f32x4 mfma16(bf16x8 a, bf16x8 b, f32x4 c) {
  return __builtin_amdgcn_mfma_f32_16x16x32_bf16(a, b, c, 0, 0, 0);
}
__device__ __forceinline__ float sigmoid_fast(float v) {
  return 1.0f / (1.0f + __expf(-v));
}
__device__ __forceinline__ float tanh_fast(float v) {
  float e = __expf(2.0f * v);
  return 1.0f - 2.0f / (e + 1.0f);
}
__device__ __forceinline__ void gl2lds(const void* g, void* l) {
  __builtin_amdgcn_global_load_lds(
      (const __attribute__((address_space(1))) unsigned int*)g,
      (__attribute__((address_space(3))) unsigned int*)l, 16, 0, 0);
}

// ---------------------------------------------------------------------------
// Weight pre-pack: fp32 W[out=512][in=512] -> bf16 B-fragments.
// Frag (gate g, kstep f, colfrag c): lane l holds 8 bf16 =
//   W[c*16 + (l&15)][f*32 + (l>>4)*8 + 0..7]
// elem index = ((g*16+f)*32 + c)*512 + l*8 + e.  Gates: rx,zx,rh,zh,nx,nh.
// ---------------------------------------------------------------------------
__global__ void prepack_weights(const float* __restrict__ W0, const float* __restrict__ W1,
                                const float* __restrict__ W2, const float* __restrict__ W3,
                                const float* __restrict__ W4, const float* __restrict__ W5,
                                unsigned short* __restrict__ out) {
  int idx = blockIdx.x * 256 + threadIdx.x;
  int e = idx & 7;
  int l = (idx >> 3) & 63;
  int c = (idx >> 9) & 31;
  int f = (idx >> 14) & 15;
  int g = idx >> 18;
  const float* W = (g == 0) ? W0 : (g == 1) ? W1 : (g == 2) ? W2
                 : (g == 3) ? W3 : (g == 4) ? W4 : W5;
  int row = c * 16 + (l & 15);
  int kk  = f * 32 + ((l >> 4) << 3) + e;
  out[idx] = f2bf(W[row * DIM + kk]);
}

// fp32 -> bf16 row-major copy (x and h)
__global__ void prep_bf16(const float* __restrict__ in, unsigned short* __restrict__ ob) {
  size_t i = (size_t)(blockIdx.x * 256 + threadIdx.x) * 8;
  float4 a0 = *(const float4*)(in + i);
  float4 a1 = *(const float4*)(in + i + 4);
  union { unsigned short us[8]; uint4 v; } p;
  p.us[0] = f2bf(a0.x); p.us[1] = f2bf(a0.y); p.us[2] = f2bf(a0.z); p.us[3] = f2bf(a0.w);
  p.us[4] = f2bf(a1.x); p.us[5] = f2bf(a1.y); p.us[6] = f2bf(a1.z); p.us[7] = f2bf(a1.w);
  *(uint4*)(ob + i) = p.v;
}

// ===========================================================================
// Sweep kernels: block = 64 rows x 256 cols, 256 thr (4 waves), wave=64rx64c,
// single acc[4][4] per sweep -> 3 blocks/CU (LDS 48KB, ~170-reg budget).
// R5-proven window: {issue stage; counted vmcnt; barrier; ds_read + 16 MFMA;
// barrier}.  x A-frags via LDS pair-staging (gl2lds); h/rh A-frags direct
// per-lane global loads issued one window early (compiler-counted waits).
// ===========================================================================
#define XOFF 32768
#define LDS48 49152

// common per-sweep loop body
#define SWEEP_LOOP(GX, GH, HS)                                                 \
  do {                                                                         \
    asm volatile("s_waitcnt vmcnt(0)" ::: "memory");                           \
    __syncthreads();                                                           \
    _Pragma("unroll")                                                          \
    for (int rf_ = 0; rf_ < 4; ++rf_)                                          \
      _Pragma("unroll")                                                        \
      for (int cf_ = 0; cf_ < 4; ++cf_)                                        \
        acc[rf_][cf_] = (f32x4){0.f, 0.f, 0.f, 0.f};                           \
    stageB((GX), 0, 0);                                                        \
    stageXpair(0);                                                             \
    _Pragma("unroll 1")                                                        \
    for (int f = 0; f < 16; ++f) {                                             \
      /* W0: compute GX(f)@b0 (A=x LDS); stage GH(f)->b1 (+x pair) */          \
      stageB((GH), f, 1);                                                      \
      if (!(f & 1) && f <= 12) {                                               \
        stageXpair((f >> 1) + 1);                                              \
        asm volatile("s_waitcnt vmcnt(6)" ::: "memory");                       \
      } else {                                                                 \
        asm volatile("s_waitcnt vmcnt(4)" ::: "memory");                       \
      }                                                                        \
      __builtin_amdgcn_s_barrier();                                            \
      loadHF((HS), f);                       /* for W1; compiler-counted */    \
      readAx(f);                                                               \
      readB(0);                                                                \
      _Pragma("unroll")                                                        \
      for (int rf_ = 0; rf_ < 4; ++rf_)                                        \
        _Pragma("unroll")                                                      \
        for (int cf_ = 0; cf_ < 4; ++cf_)                                      \
          acc[rf_][cf_] = mfma16(af[rf_], bfr[cf_], acc[rf_][cf_]);            \
      __builtin_amdgcn_s_barrier();                                            \
      /* W1: compute GH(f)@b1 (A=hf regs); stage GX(f+1)->b0 */                \
      if (f < 15) {                                                            \
        stageB((GX), f + 1, 0);                                                \
        asm volatile("s_waitcnt vmcnt(8)" ::: "memory");                       \
      } else {                                                                 \
        asm volatile("s_waitcnt vmcnt(4)" ::: "memory");                       \
      }                                                                        \
      __builtin_amdgcn_s_barrier();                                            \
      readB(1);                                                                \
      _Pragma("unroll")                                                        \
      for (int rf_ = 0; rf_ < 4; ++rf_)                                        \
        _Pragma("unroll")                                                      \
        for (int cf_ = 0; cf_ < 4; ++cf_)                                      \
          acc[rf_][cf_] = mfma16(hf[rf_], bfr[cf_], acc[rf_][cf_]);            \
      __builtin_amdgcn_s_barrier();                                            \
    }                                                                          \
  } while (0)

#define SWEEP_HELPERS()                                                        \
  const int tid = threadIdx.x, lane = tid & 63, w = tid >> 6;                  \
  const int bid = blockIdx.x;                                                  \
  const int swz = (bid & 7) * 512 + (bid >> 3);   /* 4096 = 8*512, bijective */\
  const int panel = swz >> 1, ch = swz & 1;                                    \
  const int row0 = panel * 64;                                                 \
  const int lr = lane & 15, lk = lane >> 4;                                    \
  f32x4 acc[4][4];                                                             \
  bf16x8 af[4], hf[4], bfr[4];                                                 \
  auto stageB = [&](int g, int f, int buf) {   /* 16KB, 4 gl2lds/thr */        \
    const unsigned char* src = WB + (size_t)(g * 16 + f) * 32768 + ch * 16384; \
    _Pragma("unroll")                                                          \
    for (int it = 0; it < 4; ++it) {                                           \
      int o = (it * 256 + tid) * 16;                                           \
      gl2lds(src + o, &lds[buf * 16384 + o]);                                  \
    }                                                                          \
  };                                                                           \
  auto stageXpair = [&](int p) {               /* 8KB, 2 gl2lds/thr */         \
    _Pragma("unroll")                                                          \
    for (int it = 0; it < 2; ++it) {                                           \
      int cell = it * 256 + tid;                                               \
      int fh = cell >> 8, rf = (cell >> 6) & 3, l = cell & 63;                 \
      const unsigned short* s = xb + (size_t)(row0 + rf * 16 + (l & 15)) * DIM \
                                + p * 64 + fh * 32 + (l >> 4) * 8;             \
      gl2lds(s, &lds[XOFF + (p & 1) * 8192 + cell * 16]);                      \
    }                                                                          \
  };                                                                           \
  auto readAx = [&](int f) {                                                   \
    const int base = XOFF + ((f >> 1) & 1) * 8192 + (f & 1) * 4096;            \
    _Pragma("unroll")                                                          \
    for (int rf = 0; rf < 4; ++rf)                                             \
      af[rf] = *(const bf16x8*)&lds[base + rf * 1024 + lane * 16];             \
  };                                                                           \
  auto loadHF = [&](const unsigned short* hs, int f) {                         \
    _Pragma("unroll")                                                          \
    for (int rf = 0; rf < 4; ++rf)                                             \
      hf[rf] = *(const bf16x8*)(hs + (size_t)(row0 + rf * 16 + lr) * DIM       \
                                + f * 32 + lk * 8);                            \
  };                                                                           \
  auto readB = [&](int buf) {                                                  \
    _Pragma("unroll")                                                          \
    for (int cf = 0; cf < 4; ++cf)                                             \
      bfr[cf] = *(const bf16x8*)&lds[buf * 16384 + (w * 4 + cf) * 1024         \
                                     + lane * 16];                             \
  }

// ---- k1: sweep Z (z = sigmoid -> out fp32) + sweep R (rh -> rhb bf16) ----
__global__ __launch_bounds__(256, 3)
void gru_k1(const unsigned short* __restrict__ xb,
            const unsigned short* __restrict__ hb,
            unsigned short* __restrict__ rhb,
            const unsigned char* __restrict__ WB,
            const float* __restrict__ b_rx, const float* __restrict__ b_rh,
            const float* __restrict__ b_zx, const float* __restrict__ b_zh,
            float* __restrict__ out) {
  __shared__ __align__(1024) unsigned char lds[LDS48];
  SWEEP_HELPERS();

  // ===== sweep Z: gates zx(1), zh(3), A_h = hb =====
  SWEEP_LOOP(1, 3, hb);
#pragma unroll
  for (int cf = 0; cf < 4; ++cf) {
    const int col = ch * 256 + (w * 4 + cf) * 16 + lr;
    const float bz = b_zx[col] + b_zh[col];
#pragma unroll
    for (int rf = 0; rf < 4; ++rf)
#pragma unroll
      for (int j = 0; j < 4; ++j) {
        const size_t off = (size_t)(row0 + rf * 16 + lk * 4 + j) * DIM + col;
        out[off] = sigmoid_fast(acc[rf][cf][j] + bz);
      }
  }

  // ===== sweep R: gates rx(0), rh(2); rh_val = sigmoid(.)*h -> rhb =====
  SWEEP_LOOP(0, 2, hb);
#pragma unroll
  for (int cf = 0; cf < 4; ++cf) {
    const int col = ch * 256 + (w * 4 + cf) * 16 + lr;
    const float br = b_rx[col] + b_rh[col];
#pragma unroll
    for (int rf = 0; rf < 4; ++rf)
#pragma unroll
      for (int j = 0; j < 4; ++j) {
        const size_t off = (size_t)(row0 + rf * 16 + lk * 4 + j) * DIM + col;
        const float rv = sigmoid_fast(acc[rf][cf][j] + br);
        rhb[off] = f2bf(rv * bf2f(hb[off]));
      }
  }
}

// ---- k2: sweep N (nx, nh with A=rhb) + final combine ----
__global__ __launch_bounds__(256, 3)
void gru_k2(const unsigned short* __restrict__ xb,
            const unsigned short* __restrict__ hb,
            const unsigned short* __restrict__ rhb,
            const unsigned char* __restrict__ WB,
            const float* __restrict__ b_nx, const float* __restrict__ b_nh,
            float* __restrict__ out) {
  __shared__ __align__(1024) unsigned char lds[LDS48];
  SWEEP_HELPERS();

  // ===== sweep N: gates nx(4), nh(5), A_h = rhb =====
  SWEEP_LOOP(4, 5, rhb);
#pragma unroll
  for (int cf = 0; cf < 4; ++cf) {
    const int col = ch * 256 + (w * 4 + cf) * 16 + lr;
    const float bn = b_nx[col] + b_nh[col];
#pragma unroll
    for (int rf = 0; rf < 4; ++rf)
#pragma unroll
      for (int j = 0; j < 4; ++j) {
        const size_t off = (size_t)(row0 + rf * 16 + lk * 4 + j) * DIM + col;
        const float nv = tanh_fast(acc[rf][cf][j] + bn);
        const float zv = out[off];               // z staged by k1
        out[off] = (1.0f - zv) * nv + zv * bf2f(hb[off]);
      }
  }
}

extern "C" void kernel_launch(void* const* d_in, const int* in_sizes, int n_in,
                              void* d_out, int out_size, void* d_ws, size_t ws_size,
                              hipStream_t stream) {
  const float* x    = (const float*)d_in[0];
  const float* h    = (const float*)d_in[1];
  const float* W_rx = (const float*)d_in[2];
  const float* b_rx = (const float*)d_in[3];
  const float* W_rh = (const float*)d_in[4];
  const float* b_rh = (const float*)d_in[5];
  const float* W_zx = (const float*)d_in[6];
  const float* b_zx = (const float*)d_in[7];
  const float* W_zh = (const float*)d_in[8];
  const float* b_zh = (const float*)d_in[9];
  const float* W_nx = (const float*)d_in[10];
  const float* b_nx = (const float*)d_in[11];
  const float* W_nh = (const float*)d_in[12];
  const float* b_nh = (const float*)d_in[13];

  unsigned char* ws = (unsigned char*)d_ws;
  unsigned short* wpack = (unsigned short*)ws;                   // 3 MiB
  const size_t SEG = (size_t)NROWS * DIM * 2;                    // 128 MiB
  unsigned short* xb  = (unsigned short*)(ws + (4ull << 20));
  unsigned short* hb  = (unsigned short*)(ws + (4ull << 20) + SEG);
  unsigned short* rhb = (unsigned short*)(ws + (4ull << 20) + 2 * SEG);
  // need 388 MiB -- proven available (R11 main path ran on this harness)

  // gate order: rx, zx, rh, zh, nx, nh
  prepack_weights<<<6144, 256, 0, stream>>>(W_rx, W_zx, W_rh, W_zh, W_nx, W_nh, wpack);
  prep_bf16<<<32768, 256, 0, stream>>>(x, xb);
  prep_bf16<<<32768, 256, 0, stream>>>(h, hb);
  gru_k1<<<4096, 256, 0, stream>>>(xb, hb, rhb, (const unsigned char*)wpack,
                                   b_rx, b_rh, b_zx, b_zh, (float*)d_out);
  gru_k2<<<4096, 256, 0, stream>>>(xb, hb, rhb, (const unsigned char*)wpack,
                                   b_nx, b_nh, (float*)d_out);
}